// Round 8
// baseline (246.983 us; speedup 1.0000x reference)
//
#include <hip/hip_runtime.h>
#include <hip/hip_bf16.h>
#include <stdint.h>

// Problem: B=4, T_p=T_f=16, S=256, D=2048, H=16, hd=128, T=64 tokens.
// Inputs f32; outputs f32. GEMMs in bf16 MFMA (f32 accumulate).
// R8 = R7 + (a) single-barrier double-buffered GEMM staging (issue next
// K-tile's global_load_lds before computing current; one __syncthreads per
// step so the vmcnt drain overlaps compute)  (b) prep_w and mean_stage1
// merged into one launch (independent block ranges).

using bf16x8v = __attribute__((ext_vector_type(8))) __bf16;
using f32x4v  = __attribute__((ext_vector_type(4))) float;

union Pack8 { __bf16 h[8]; uint4 u; };

// Swizzled element offset in a [rows][64 bf16] LDS tile:
// row stride 64 el (128B), 8 chunks of 8 el; chunk c lives at c^(row&7).
__device__ __forceinline__ int swz(int r, int c) {
    return (r << 6) + ((c ^ (r & 7)) << 3);
}

// ---------------------------------------------------------------------------
// 0) Fused independent preprocessing:
//    blocks 0..2047    : mean partial sums (s-chunks of 32) -> partials
//    blocks 2048..6143 : transpose+convert W_qkv / W_proj -> bf16 [N][2048]
__global__ __launch_bounds__(256) void prep_mean_kernel(
    const float* __restrict__ v_p, const float* __restrict__ v_f,
    float* __restrict__ partials,
    const float* __restrict__ W_qkv, const float* __restrict__ W_proj,
    __bf16* __restrict__ Wt_qkv, __bf16* __restrict__ Wt_proj)
{
    __shared__ float Ls[64][68];
    int bid0 = blockIdx.x;
    if (bid0 < 2048) {
        // ---- mean partial sums ----
        int bid = bid0;
        int which  = bid >> 10;         // 0: v_p, 1: v_f
        int rem    = bid & 1023;
        int row    = rem >> 4;          // 0..63 = b*16+t
        int dchunk = (rem >> 3) & 1;
        int schunk = rem & 7;
        int d = (dchunk << 10) + (threadIdx.x << 2);
        const float* src = (which ? v_f : v_p) + ((size_t)row << 19)
                         + ((size_t)(schunk << 5) << 11) + d;
        float4 a = {0.f, 0.f, 0.f, 0.f};
        #pragma unroll 8
        for (int s = 0; s < 32; ++s) {
            float4 x = *reinterpret_cast<const float4*>(src + ((size_t)s << 11));
            a.x += x.x; a.y += x.y; a.z += x.z; a.w += x.w;
        }
        int pr = which * 64 + row;
        *reinterpret_cast<float4*>(&partials[(size_t)((pr << 3) + schunk) * 2048 + d]) = a;
    } else {
        // ---- weight transpose + bf16 convert ----
        int bid = bid0 - 2048;
        const float* src; __bf16* dst; int N, tile;
        if (bid < 3072) { src = W_qkv;  dst = Wt_qkv;  N = 6144; tile = bid; }
        else            { src = W_proj; dst = Wt_proj; N = 2048; tile = bid - 3072; }
        int tiles_n = N >> 6;
        int tn = tile % tiles_n;
        int tk = tile / tiles_n;
        int t = threadIdx.x;
        int rb = t >> 4;            // 0..15
        int c4 = (t & 15) << 2;     // 0..60
        #pragma unroll
        for (int s = 0; s < 4; ++s) {
            int r = rb + (s << 4);
            float4 v = *reinterpret_cast<const float4*>(
                src + (size_t)(tk * 64 + r) * N + tn * 64 + c4);
            *reinterpret_cast<float4*>(&Ls[r][c4]) = v;
        }
        __syncthreads();
        int c  = t >> 2;            // 0..63
        int r0 = (t & 3) << 4;      // 0,16,32,48
        Pack8 p0, p1;
        #pragma unroll
        for (int i = 0; i < 8; ++i) p0.h[i] = (__bf16)Ls[r0 + i][c];
        #pragma unroll
        for (int i = 0; i < 8; ++i) p1.h[i] = (__bf16)Ls[r0 + 8 + i][c];
        __bf16* drow = dst + (size_t)(tn * 64 + c) * 2048 + tk * 64 + r0;
        *reinterpret_cast<uint4*>(drow)     = p0.u;
        *reinterpret_cast<uint4*>(drow + 8) = p1.u;
    }
}

// ---------------------------------------------------------------------------
// 1) finish tokens: blocks 0..127 reduce means -> rows 0..31/batch;
//    blocks 128..255 pack audio -> rows 32..63/batch. tokens_bf out.
__global__ __launch_bounds__(256) void tokens_finish_kernel(
    const float* __restrict__ partials, const float* __restrict__ a_p,
    const float* __restrict__ a_f, __bf16* __restrict__ tokens_bf)
{
    int bid = blockIdx.x;
    if (bid < 128) {
        int idx = (bid * 256 + threadIdx.x) * 8;   // 0..262143
        int r = idx >> 11;            // 0..127 = which*64 + b*16+tt
        int d = idx & 2047;
        float s[8];
        #pragma unroll
        for (int i = 0; i < 8; ++i) s[i] = 0.f;
        #pragma unroll
        for (int sc = 0; sc < 8; ++sc) {
            const float* p = partials + (size_t)((r << 3) + sc) * 2048 + d;
            float4 x0 = *reinterpret_cast<const float4*>(p);
            float4 x1 = *reinterpret_cast<const float4*>(p + 4);
            s[0] += x0.x; s[1] += x0.y; s[2] += x0.z; s[3] += x0.w;
            s[4] += x1.x; s[5] += x1.y; s[6] += x1.z; s[7] += x1.w;
        }
        const float inv = 1.f / 256.f;
        int which = r >> 6, rr = r & 63;
        int b = rr >> 4, tt = rr & 15;
        int tokrow = b * 64 + which * 16 + tt;
        Pack8 p;
        #pragma unroll
        for (int i = 0; i < 8; ++i) p.h[i] = (__bf16)(s[i] * inv);
        *reinterpret_cast<uint4*>(&tokens_bf[(size_t)tokrow * 2048 + d]) = p.u;
    } else {
        int g = (bid - 128) * 256 + threadIdx.x;   // 8-elem group, 0..32767
        int which = g >> 14;
        int j = g & 16383;
        int b = j >> 12;
        int rr = j & 4095;
        int tt = rr >> 8;
        int gq = rr & 255;
        const float* src = (which ? a_f : a_p) + (size_t)(b * 16 + tt) * 2048 + gq * 8;
        float4 x0 = *reinterpret_cast<const float4*>(src);
        float4 x1 = *reinterpret_cast<const float4*>(src + 4);
        Pack8 p;
        p.h[0] = (__bf16)x0.x; p.h[1] = (__bf16)x0.y; p.h[2] = (__bf16)x0.z; p.h[3] = (__bf16)x0.w;
        p.h[4] = (__bf16)x1.x; p.h[5] = (__bf16)x1.y; p.h[6] = (__bf16)x1.z; p.h[7] = (__bf16)x1.w;
        int tokrow = b * 64 + 32 + which * 16 + tt;
        *reinterpret_cast<uint4*>(&tokens_bf[(size_t)tokrow * 2048 + gq * 8]) = p.u;
    }
}

// ---------------------------------------------------------------------------
// 2) bf16 MFMA GEMM: C[64*g.y][N] = A * Bt^T (+bias).
// 64x64 tile, BK=64, 4 waves. Double-buffered global_load_lds staging with a
// SINGLE barrier per K-step: barrier -> issue loads for kt+1 into buf^1 ->
// compute on buf. The compiler's vmcnt(0) drain at the next barrier then
// overlaps the whole compute phase. LDS dest linear (wave base + lane*16),
// global source pre-swizzled (chunk ^(row&7)); ds_read uses swz() as R4.
__global__ __launch_bounds__(256) void gemm_bf16_kernel(
    const __bf16* __restrict__ A, const __bf16* __restrict__ Bt,
    const float* __restrict__ bias, float* __restrict__ C, int N)
{
    __shared__ __bf16 As[2][4096];
    __shared__ __bf16 Bs[2][4096];
    const int t = threadIdx.x;
    const int m0 = blockIdx.y << 6;
    const int n0 = blockIdx.x << 6;
    const int lane = t & 63;
    const int w = t >> 6;                // wave 0..3
    const int wm = w << 4;               // wave's m offset
    const int lrow = lane & 15;
    const int lk = lane >> 4;            // 0..3
    const int srl = lane >> 3;           // 0..7 (row within 8-row call)
    const int schunk = lane & 7;

    f32x4v acc[4] = {{0.f,0.f,0.f,0.f},{0.f,0.f,0.f,0.f},
                     {0.f,0.f,0.f,0.f},{0.f,0.f,0.f,0.f}};

    // staging geometry: wave w stages rows w*16 .. w*16+15 of each tile
    int row_c0 = (w << 4) + srl;         // rows w*16 + 0..7
    int row_c1 = row_c0 + 8;             // rows w*16 + 8..15
    const __bf16* gA0 = A  + (size_t)(m0 + row_c0) * 2048 + ((schunk ^ (row_c0 & 7)) << 3);
    const __bf16* gA1 = A  + (size_t)(m0 + row_c1) * 2048 + ((schunk ^ (row_c1 & 7)) << 3);
    const __bf16* gB0 = Bt + (size_t)(n0 + row_c0) * 2048 + ((schunk ^ (row_c0 & 7)) << 3);
    const __bf16* gB1 = Bt + (size_t)(n0 + row_c1) * 2048 + ((schunk ^ (row_c1 & 7)) << 3);
    const int wb0 = (w << 4) << 6;               // wave LDS elem base (rows 0..7)
    const int wb1 = ((w << 4) + 8) << 6;         // rows 8..15

#define GLDS_ISSUE(kt, buf)                                                     \
    do {                                                                        \
        int ko_ = (kt) << 6;                                                    \
        __builtin_amdgcn_global_load_lds(                                       \
            (const __attribute__((address_space(1))) void*)(gA0 + ko_),         \
            (__attribute__((address_space(3))) void*)&As[(buf)][wb0], 16, 0, 0);\
        __builtin_amdgcn_global_load_lds(                                       \
            (const __attribute__((address_space(1))) void*)(gA1 + ko_),         \
            (__attribute__((address_space(3))) void*)&As[(buf)][wb1], 16, 0, 0);\
        __builtin_amdgcn_global_load_lds(                                       \
            (const __attribute__((address_space(1))) void*)(gB0 + ko_),         \
            (__attribute__((address_space(3))) void*)&Bs[(buf)][wb0], 16, 0, 0);\
        __builtin_amdgcn_global_load_lds(                                       \
            (const __attribute__((address_space(1))) void*)(gB1 + ko_),         \
            (__attribute__((address_space(3))) void*)&Bs[(buf)][wb1], 16, 0, 0);\
    } while (0)

    // prologue: stage K-tile 0 into buffer 0
    GLDS_ISSUE(0, 0);

    for (int kt = 0; kt < 32; ++kt) {
        int cur = kt & 1;
        __syncthreads();                 // drains vmcnt: buf[cur] ready; all
                                         // waves done reading buf[cur^1]
        if (kt < 31) GLDS_ISSUE(kt + 1, cur ^ 1);
        #pragma unroll
        for (int s = 0; s < 2; ++s) {
            int cA = (s << 2) + lk;
            bf16x8v af = *reinterpret_cast<const bf16x8v*>(&As[cur][swz(wm + lrow, cA)]);
            #pragma unroll
            for (int j = 0; j < 4; ++j) {
                bf16x8v bf = *reinterpret_cast<const bf16x8v*>(&Bs[cur][swz((j << 4) + lrow, cA)]);
                acc[j] = __builtin_amdgcn_mfma_f32_16x16x32_bf16(af, bf, acc[j], 0, 0, 0);
            }
        }
    }
#undef GLDS_ISSUE
    // epilogue: C/D layout col=lane&15, row=(lane>>4)*4+reg
    #pragma unroll
    for (int j = 0; j < 4; ++j) {
        int col = n0 + (j << 4) + lrow;
        float bv = bias ? bias[col] : 0.f;
        #pragma unroll
        for (int e = 0; e < 4; ++e) {
            int row = m0 + wm + (lk << 2) + e;
            C[(size_t)row * N + col] = acc[j][e] + bv;
        }
    }
}

// ---------------------------------------------------------------------------
// 3) Attention per (b,h) with RoPE fused into q/k staging; causal softmax;
// bf16 out. Compute section identical to R4-verified kernel.
__global__ __launch_bounds__(256) void attn_kernel(
    const float* __restrict__ qkv, __bf16* __restrict__ attn_out)
{
    __shared__ float q_s[64 * 128];   // reused as p_s[64][65]
    __shared__ float k_s[64 * 128];   // reused as v_s
    int b = blockIdx.x >> 4;
    int h = blockIdx.x & 15;
    int tid = threadIdx.x;
    const float* base = qkv + (size_t)(b * 64) * 6144 + h * 128;
    // RoPE-fused staging: task = (row tq, low-half float4 group dg).
    const float L2 = 0.20762050593046012f;   // log2(10000)/64
    #pragma unroll
    for (int r = 0; r < 4; ++r) {
        int idx = tid + (r << 8);     // 0..1023
        int tq = idx >> 4;            // 0..63
        int d = (idx & 15) << 2;      // 0..60 (low half)
        const float* srcr = base + (size_t)tq * 6144;
        float4 q1 = *reinterpret_cast<const float4*>(srcr + d);
        float4 q2 = *reinterpret_cast<const float4*>(srcr + d + 64);
        float4 k1 = *reinterpret_cast<const float4*>(srcr + 2048 + d);
        float4 k2 = *reinterpret_cast<const float4*>(srcr + 2048 + d + 64);
        float ft = (float)tq;
        float a0 = ft * exp2f(-(float)(d + 0) * L2);
        float a1 = ft * exp2f(-(float)(d + 1) * L2);
        float a2 = ft * exp2f(-(float)(d + 2) * L2);
        float a3 = ft * exp2f(-(float)(d + 3) * L2);
        float c0 = cosf(a0), s0 = sinf(a0);
        float c1 = cosf(a1), s1 = sinf(a1);
        float c2 = cosf(a2), s2 = sinf(a2);
        float c3 = cosf(a3), s3 = sinf(a3);
        float4 qa, qb, ka, kb;
        qa.x = q1.x * c0 - q2.x * s0;  qb.x = q2.x * c0 + q1.x * s0;
        qa.y = q1.y * c1 - q2.y * s1;  qb.y = q2.y * c1 + q1.y * s1;
        qa.z = q1.z * c2 - q2.z * s2;  qb.z = q2.z * c2 + q1.z * s2;
        qa.w = q1.w * c3 - q2.w * s3;  qb.w = q2.w * c3 + q1.w * s3;
        ka.x = k1.x * c0 - k2.x * s0;  kb.x = k2.x * c0 + k1.x * s0;
        ka.y = k1.y * c1 - k2.y * s1;  kb.y = k2.y * c1 + k1.y * s1;
        ka.z = k1.z * c2 - k2.z * s2;  kb.z = k2.z * c2 + k1.z * s2;
        ka.w = k1.w * c3 - k2.w * s3;  kb.w = k2.w * c3 + k1.w * s3;
        *reinterpret_cast<float4*>(&q_s[tq * 128 + d])      = qa;
        *reinterpret_cast<float4*>(&q_s[tq * 128 + d + 64]) = qb;
        *reinterpret_cast<float4*>(&k_s[tq * 128 + d])      = ka;
        *reinterpret_cast<float4*>(&k_s[tq * 128 + d + 64]) = kb;
    }
    __syncthreads();
    int qi = tid >> 2;
    int g  = tid & 3;
    float pv[16];
    #pragma unroll
    for (int j = 0; j < 16; ++j) pv[j] = 0.f;
    for (int d = 0; d < 128; d += 4) {
        float4 a = *reinterpret_cast<const float4*>(&q_s[qi * 128 + d]);
        #pragma unroll
        for (int j = 0; j < 16; ++j) {
            int ki = (j << 2) + g;
            float4 bb = *reinterpret_cast<const float4*>(&k_s[ki * 128 + d]);
            pv[j] += a.x * bb.x + a.y * bb.y + a.z * bb.z + a.w * bb.w;
        }
    }
    const float scale = 0.0883883476483184405f;   // 128^-0.5
    float m = -1e30f;
    #pragma unroll
    for (int j = 0; j < 16; ++j) {
        int ki = (j << 2) + g;
        pv[j] = (ki <= qi) ? pv[j] * scale : -1e30f;
        m = fmaxf(m, pv[j]);
    }
    m = fmaxf(m, __shfl_xor(m, 1));
    m = fmaxf(m, __shfl_xor(m, 2));
    float l = 0.f;
    #pragma unroll
    for (int j = 0; j < 16; ++j) {
        float e = (pv[j] > -1e29f) ? expf(pv[j] - m) : 0.f;
        pv[j] = e;
        l += e;
    }
    l += __shfl_xor(l, 1);
    l += __shfl_xor(l, 2);
    float inv_l = 1.f / l;
    __syncthreads();
    float* p_s = q_s;
    #pragma unroll
    for (int j = 0; j < 16; ++j) p_s[qi * 65 + (j << 2) + g] = pv[j] * inv_l;
    float* v_s = k_s;
    #pragma unroll
    for (int r = 0; r < 8; ++r) {
        int idx = tid + (r << 8);
        int t = idx >> 5;
        int d = (idx & 31) << 2;
        *reinterpret_cast<float4*>(&v_s[t * 128 + d]) =
            *reinterpret_cast<const float4*>(base + (size_t)t * 6144 + 4096 + d);
    }
    __syncthreads();
    int d0 = g << 5;
    float4 acc[8];
    #pragma unroll
    for (int u = 0; u < 8; ++u) acc[u] = {0.f, 0.f, 0.f, 0.f};
    for (int ki = 0; ki < 64; ++ki) {
        float p = p_s[qi * 65 + ki];
        #pragma unroll
        for (int u = 0; u < 8; ++u) {
            float4 vv = *reinterpret_cast<const float4*>(&v_s[ki * 128 + d0 + (u << 2)]);
            acc[u].x += p * vv.x;
            acc[u].y += p * vv.y;
            acc[u].z += p * vv.z;
            acc[u].w += p * vv.w;
        }
    }
    __bf16* orow = attn_out + (size_t)(b * 64 + qi) * 2048 + h * 128 + d0;
    #pragma unroll
    for (int v = 0; v < 4; ++v) {
        Pack8 p;
        float4 a0 = acc[2 * v], a1 = acc[2 * v + 1];
        p.h[0] = (__bf16)a0.x; p.h[1] = (__bf16)a0.y; p.h[2] = (__bf16)a0.z; p.h[3] = (__bf16)a0.w;
        p.h[4] = (__bf16)a1.x; p.h[5] = (__bf16)a1.y; p.h[6] = (__bf16)a1.z; p.h[7] = (__bf16)a1.w;
        *reinterpret_cast<uint4*>(orow + v * 8) = p.u;
    }
}

// ---------------------------------------------------------------------------
// 4) Outputs: blocks 0..2047 broadcast video; 2048..2175 copy audio. f32.
__global__ __launch_bounds__(256) void outputs_kernel(
    const float* __restrict__ outp, float* __restrict__ d_out)
{
    int bid = blockIdx.x;
    if (bid < 2048) {
        int which = bid >> 10;
        int rem = bid & 1023;
        int row = rem >> 4;             // b*16 + t
        int schunk = rem & 15;
        int b = row >> 4;
        int t = row & 15;
        const float* src = outp + (size_t)(b * 64 + (which << 4) + t) * 2048 + threadIdx.x * 8;
        float4 o0 = *reinterpret_cast<const float4*>(src);
        float4 o1 = *reinterpret_cast<const float4*>(src + 4);
        size_t base = (size_t)which * 33554432 +
                      ((size_t)row * 256 + (size_t)schunk * 16) * 2048 + threadIdx.x * 8;
        float* dst = d_out + base;
        #pragma unroll
        for (int s = 0; s < 16; ++s) {
            *reinterpret_cast<float4*>(dst + (size_t)s * 2048)     = o0;
            *reinterpret_cast<float4*>(dst + (size_t)s * 2048 + 4) = o1;
        }
    } else {
        int g = (bid - 2048) * 256 + threadIdx.x;   // 8-float group, 0..32767
        int which = g >> 15;
        int j = g & 32767;
        int b = j >> 13;
        int rr = j & 8191;
        int tt = rr >> 9;
        int gq = rr & 511;
        // NOTE: audio groups are 8 floats; recompute indices for 8-float granularity
        (void)which; (void)j; (void)b; (void)rr; (void)tt; (void)gq;
        int g8 = (bid - 2048) * 256 + threadIdx.x;  // 0..32767 (128 blocks)
        int which8 = g8 >> 14;
        int j8 = g8 & 16383;
        int b8 = j8 >> 12;
        int rr8 = j8 & 4095;
        int tt8 = rr8 >> 8;
        int gq8 = rr8 & 255;
        const float* src = outp + (size_t)(b8 * 64 + 32 + (which8 << 4) + tt8) * 2048 + gq8 * 8;
        float4 x0 = *reinterpret_cast<const float4*>(src);
        float4 x1 = *reinterpret_cast<const float4*>(src + 4);
        float* dst = d_out + 67108864 + (size_t)which8 * 131072 +
                     (size_t)(b8 * 16 + tt8) * 2048 + gq8 * 8;
        *reinterpret_cast<float4*>(dst)     = x0;
        *reinterpret_cast<float4*>(dst + 4) = x1;
    }
}

// ---------------------------------------------------------------------------
extern "C" void kernel_launch(void* const* d_in, const int* in_sizes, int n_in,
                              void* d_out, int out_size, void* d_ws, size_t ws_size,
                              hipStream_t stream)
{
    const float* v_p    = (const float*)d_in[0];
    const float* v_f    = (const float*)d_in[1];
    const float* a_p    = (const float*)d_in[2];
    const float* a_f    = (const float*)d_in[3];
    const float* W_qkv  = (const float*)d_in[4];
    const float* W_proj = (const float*)d_in[5];
    const float* b_proj = (const float*)d_in[6];
    float* out_f = (float*)d_out;

    char* ws = (char*)d_ws;
    __bf16* tokens_bf = (__bf16*)(ws);                       // 1 MB
    __bf16* Wt_qkv    = (__bf16*)(ws + 1048576);             // 24 MB
    __bf16* Wt_proj   = (__bf16*)(ws + 26214400);            // 8 MB
    float*  qkv       = (float*)(ws + 34603008);             // 6 MB
    __bf16* attn_bf   = (__bf16*)(ws + 40894464);            // 1 MB
    float*  outp      = (float*)(ws + 41943040);             // 2 MB
    float*  partials  = (float*)(ws + 44040192);             // 8 MB

    prep_mean_kernel<<<6144, 256, 0, stream>>>(v_p, v_f, partials,
                                               W_qkv, W_proj, Wt_qkv, Wt_proj);
    tokens_finish_kernel<<<256, 256, 0, stream>>>(partials, a_p, a_f, tokens_bf);
    gemm_bf16_kernel<<<dim3(96, 4), 256, 0, stream>>>(tokens_bf, Wt_qkv, nullptr, qkv, 6144);
    attn_kernel<<<64, 256, 0, stream>>>(qkv, attn_bf);
    gemm_bf16_kernel<<<dim3(32, 4), 256, 0, stream>>>(attn_bf, Wt_proj, b_proj, outp, 2048);
    outputs_kernel<<<2176, 256, 0, stream>>>(outp, out_f);
}

// Round 9
// 218.703 us; speedup vs baseline: 1.1293x; 1.1293x over previous
//
#include <hip/hip_runtime.h>
#include <hip/hip_bf16.h>
#include <stdint.h>

// Problem: B=4, T_p=T_f=16, S=256, D=2048, H=16, hd=128, T=64 tokens.
// Inputs f32; outputs f32. GEMMs in bf16 MFMA (f32 accumulate).
// R9 = R8 - dbuf GEMM (revert to R7 single-buffer gload_lds)
//        + attn LDS XOR-chunk swizzle (T2) and interleaved PV dims
//          (kills the 16-way q / 4-way k / 4-way v bank conflicts).

using bf16x8v = __attribute__((ext_vector_type(8))) __bf16;
using f32x4v  = __attribute__((ext_vector_type(4))) float;

union Pack8 { __bf16 h[8]; uint4 u; };
union Pack4 { __bf16 h[4]; uint2 u; };

// Swizzled element offset in a [rows][64 bf16] LDS tile (GEMM):
// row stride 64 el (128B), 8 chunks of 8 el; chunk c lives at c^(row&7).
__device__ __forceinline__ int swz(int r, int c) {
    return (r << 6) + ((c ^ (r & 7)) << 3);
}
// Swizzled float4-chunk offset in a [64 rows][128 f32] LDS tile (attn):
// 32 chunks of 4 f32 per row; chunk c lives at c^(row&31).
__device__ __forceinline__ int aswz(int r, int c) {
    return (r << 7) + ((c ^ (r & 31)) << 2);
}

// ---------------------------------------------------------------------------
// 0) Fused independent preprocessing:
//    blocks 0..2047    : mean partial sums (s-chunks of 32) -> partials
//    blocks 2048..6143 : transpose+convert W_qkv / W_proj -> bf16 [N][2048]
__global__ __launch_bounds__(256) void prep_mean_kernel(
    const float* __restrict__ v_p, const float* __restrict__ v_f,
    float* __restrict__ partials,
    const float* __restrict__ W_qkv, const float* __restrict__ W_proj,
    __bf16* __restrict__ Wt_qkv, __bf16* __restrict__ Wt_proj)
{
    __shared__ float Ls[64][68];
    int bid0 = blockIdx.x;
    if (bid0 < 2048) {
        int bid = bid0;
        int which  = bid >> 10;         // 0: v_p, 1: v_f
        int rem    = bid & 1023;
        int row    = rem >> 4;          // 0..63 = b*16+t
        int dchunk = (rem >> 3) & 1;
        int schunk = rem & 7;
        int d = (dchunk << 10) + (threadIdx.x << 2);
        const float* src = (which ? v_f : v_p) + ((size_t)row << 19)
                         + ((size_t)(schunk << 5) << 11) + d;
        float4 a = {0.f, 0.f, 0.f, 0.f};
        #pragma unroll 8
        for (int s = 0; s < 32; ++s) {
            float4 x = *reinterpret_cast<const float4*>(src + ((size_t)s << 11));
            a.x += x.x; a.y += x.y; a.z += x.z; a.w += x.w;
        }
        int pr = which * 64 + row;
        *reinterpret_cast<float4*>(&partials[(size_t)((pr << 3) + schunk) * 2048 + d]) = a;
    } else {
        int bid = bid0 - 2048;
        const float* src; __bf16* dst; int N, tile;
        if (bid < 3072) { src = W_qkv;  dst = Wt_qkv;  N = 6144; tile = bid; }
        else            { src = W_proj; dst = Wt_proj; N = 2048; tile = bid - 3072; }
        int tiles_n = N >> 6;
        int tn = tile % tiles_n;
        int tk = tile / tiles_n;
        int t = threadIdx.x;
        int rb = t >> 4;            // 0..15
        int c4 = (t & 15) << 2;     // 0..60
        #pragma unroll
        for (int s = 0; s < 4; ++s) {
            int r = rb + (s << 4);
            float4 v = *reinterpret_cast<const float4*>(
                src + (size_t)(tk * 64 + r) * N + tn * 64 + c4);
            *reinterpret_cast<float4*>(&Ls[r][c4]) = v;
        }
        __syncthreads();
        int c  = t >> 2;            // 0..63
        int r0 = (t & 3) << 4;      // 0,16,32,48
        Pack8 p0, p1;
        #pragma unroll
        for (int i = 0; i < 8; ++i) p0.h[i] = (__bf16)Ls[r0 + i][c];
        #pragma unroll
        for (int i = 0; i < 8; ++i) p1.h[i] = (__bf16)Ls[r0 + 8 + i][c];
        __bf16* drow = dst + (size_t)(tn * 64 + c) * 2048 + tk * 64 + r0;
        *reinterpret_cast<uint4*>(drow)     = p0.u;
        *reinterpret_cast<uint4*>(drow + 8) = p1.u;
    }
}

// ---------------------------------------------------------------------------
// 1) finish tokens: blocks 0..127 reduce means -> rows 0..31/batch;
//    blocks 128..255 pack audio -> rows 32..63/batch. tokens_bf out.
__global__ __launch_bounds__(256) void tokens_finish_kernel(
    const float* __restrict__ partials, const float* __restrict__ a_p,
    const float* __restrict__ a_f, __bf16* __restrict__ tokens_bf)
{
    int bid = blockIdx.x;
    if (bid < 128) {
        int idx = (bid * 256 + threadIdx.x) * 8;   // 0..262143
        int r = idx >> 11;            // 0..127 = which*64 + b*16+tt
        int d = idx & 2047;
        float s[8];
        #pragma unroll
        for (int i = 0; i < 8; ++i) s[i] = 0.f;
        #pragma unroll
        for (int sc = 0; sc < 8; ++sc) {
            const float* p = partials + (size_t)((r << 3) + sc) * 2048 + d;
            float4 x0 = *reinterpret_cast<const float4*>(p);
            float4 x1 = *reinterpret_cast<const float4*>(p + 4);
            s[0] += x0.x; s[1] += x0.y; s[2] += x0.z; s[3] += x0.w;
            s[4] += x1.x; s[5] += x1.y; s[6] += x1.z; s[7] += x1.w;
        }
        const float inv = 1.f / 256.f;
        int which = r >> 6, rr = r & 63;
        int b = rr >> 4, tt = rr & 15;
        int tokrow = b * 64 + which * 16 + tt;
        Pack8 p;
        #pragma unroll
        for (int i = 0; i < 8; ++i) p.h[i] = (__bf16)(s[i] * inv);
        *reinterpret_cast<uint4*>(&tokens_bf[(size_t)tokrow * 2048 + d]) = p.u;
    } else {
        int g = (bid - 128) * 256 + threadIdx.x;   // 8-elem group, 0..32767
        int which = g >> 14;
        int j = g & 16383;
        int b = j >> 12;
        int rr = j & 4095;
        int tt = rr >> 8;
        int gq = rr & 255;
        const float* src = (which ? a_f : a_p) + (size_t)(b * 16 + tt) * 2048 + gq * 8;
        float4 x0 = *reinterpret_cast<const float4*>(src);
        float4 x1 = *reinterpret_cast<const float4*>(src + 4);
        Pack8 p;
        p.h[0] = (__bf16)x0.x; p.h[1] = (__bf16)x0.y; p.h[2] = (__bf16)x0.z; p.h[3] = (__bf16)x0.w;
        p.h[4] = (__bf16)x1.x; p.h[5] = (__bf16)x1.y; p.h[6] = (__bf16)x1.z; p.h[7] = (__bf16)x1.w;
        int tokrow = b * 64 + 32 + which * 16 + tt;
        *reinterpret_cast<uint4*>(&tokens_bf[(size_t)tokrow * 2048 + gq * 8]) = p.u;
    }
}

// ---------------------------------------------------------------------------
// 2) bf16 MFMA GEMM (R7-verified): C[64*g.y][N] = A * Bt^T (+bias).
// 64x64 tile, BK=64, 4 waves. global_load_lds width=16, linear LDS dest,
// pre-swizzled global source; swizzled ds_read; MFMA/epilogue as R4.
__global__ __launch_bounds__(256) void gemm_bf16_kernel(
    const __bf16* __restrict__ A, const __bf16* __restrict__ Bt,
    const float* __restrict__ bias, float* __restrict__ C, int N)
{
    __shared__ __bf16 As[4096];
    __shared__ __bf16 Bs[4096];
    const int t = threadIdx.x;
    const int m0 = blockIdx.y << 6;
    const int n0 = blockIdx.x << 6;
    const int lane = t & 63;
    const int w = t >> 6;                // wave 0..3
    const int wm = w << 4;               // wave's m offset
    const int lrow = lane & 15;
    const int lk = lane >> 4;            // 0..3
    const int srl = lane >> 3;           // 0..7 (row within 8-row call)
    const int schunk = lane & 7;

    f32x4v acc[4] = {{0.f,0.f,0.f,0.f},{0.f,0.f,0.f,0.f},
                     {0.f,0.f,0.f,0.f},{0.f,0.f,0.f,0.f}};

    int row_c0 = (w << 4) + srl;         // rows w*16 + 0..7
    int row_c1 = row_c0 + 8;             // rows w*16 + 8..15
    const __bf16* gA0 = A  + (size_t)(m0 + row_c0) * 2048 + ((schunk ^ (row_c0 & 7)) << 3);
    const __bf16* gA1 = A  + (size_t)(m0 + row_c1) * 2048 + ((schunk ^ (row_c1 & 7)) << 3);
    const __bf16* gB0 = Bt + (size_t)(n0 + row_c0) * 2048 + ((schunk ^ (row_c0 & 7)) << 3);
    const __bf16* gB1 = Bt + (size_t)(n0 + row_c1) * 2048 + ((schunk ^ (row_c1 & 7)) << 3);
    __bf16* lA0 = &As[(w << 4) << 6];
    __bf16* lA1 = &As[((w << 4) + 8) << 6];
    __bf16* lB0 = &Bs[(w << 4) << 6];
    __bf16* lB1 = &Bs[((w << 4) + 8) << 6];

    for (int kt = 0; kt < 32; ++kt) {
        __syncthreads();
        int ko = kt << 6;
        __builtin_amdgcn_global_load_lds(
            (const __attribute__((address_space(1))) void*)(gA0 + ko),
            (__attribute__((address_space(3))) void*)lA0, 16, 0, 0);
        __builtin_amdgcn_global_load_lds(
            (const __attribute__((address_space(1))) void*)(gA1 + ko),
            (__attribute__((address_space(3))) void*)lA1, 16, 0, 0);
        __builtin_amdgcn_global_load_lds(
            (const __attribute__((address_space(1))) void*)(gB0 + ko),
            (__attribute__((address_space(3))) void*)lB0, 16, 0, 0);
        __builtin_amdgcn_global_load_lds(
            (const __attribute__((address_space(1))) void*)(gB1 + ko),
            (__attribute__((address_space(3))) void*)lB1, 16, 0, 0);
        __syncthreads();
        #pragma unroll
        for (int s = 0; s < 2; ++s) {
            int cA = (s << 2) + lk;
            bf16x8v af = *reinterpret_cast<const bf16x8v*>(&As[swz(wm + lrow, cA)]);
            #pragma unroll
            for (int j = 0; j < 4; ++j) {
                bf16x8v bf = *reinterpret_cast<const bf16x8v*>(&Bs[swz((j << 4) + lrow, cA)]);
                acc[j] = __builtin_amdgcn_mfma_f32_16x16x32_bf16(af, bf, acc[j], 0, 0, 0);
            }
        }
    }
    #pragma unroll
    for (int j = 0; j < 4; ++j) {
        int col = n0 + (j << 4) + lrow;
        float bv = bias ? bias[col] : 0.f;
        #pragma unroll
        for (int e = 0; e < 4; ++e) {
            int row = m0 + wm + (lk << 2) + e;
            C[(size_t)row * N + col] = acc[j][e] + bv;
        }
    }
}

// ---------------------------------------------------------------------------
// 3) Attention per (b,h), RoPE fused into q/k staging; causal softmax; bf16
// out. LDS tiles use aswz() XOR-chunk swizzle (T2): QK^T k-reads and PV
// v-reads conflict-free, q-reads 2-way (free). PV uses interleaved dims
// (thread (qi,g) owns dims g*4 + u*16 + 0..3) so g maps to low chunk bits.
__global__ __launch_bounds__(256) void attn_kernel(
    const float* __restrict__ qkv, __bf16* __restrict__ attn_out)
{
    __shared__ float q_s[64 * 128];   // swizzled; reused as p_s[64][65]
    __shared__ float k_s[64 * 128];   // swizzled; reused as v_s (swizzled)
    int b = blockIdx.x >> 4;
    int h = blockIdx.x & 15;
    int tid = threadIdx.x;
    const float* base = qkv + (size_t)(b * 64) * 6144 + h * 128;
    const float L2C = 0.20762050593046012f;   // log2(10000)/64
    // RoPE-fused staging: task = (row tq, low-half chunk cg of 4 dims).
    #pragma unroll
    for (int r = 0; r < 4; ++r) {
        int idx = tid + (r << 8);     // 0..1023
        int tq = idx >> 4;            // 0..63
        int cg = idx & 15;            // low-half float4 chunk 0..15
        int d = cg << 2;
        const float* srcr = base + (size_t)tq * 6144;
        float4 q1 = *reinterpret_cast<const float4*>(srcr + d);
        float4 q2 = *reinterpret_cast<const float4*>(srcr + d + 64);
        float4 k1 = *reinterpret_cast<const float4*>(srcr + 2048 + d);
        float4 k2 = *reinterpret_cast<const float4*>(srcr + 2048 + d + 64);
        float ft = (float)tq;
        float a0 = ft * exp2f(-(float)(d + 0) * L2C);
        float a1 = ft * exp2f(-(float)(d + 1) * L2C);
        float a2 = ft * exp2f(-(float)(d + 2) * L2C);
        float a3 = ft * exp2f(-(float)(d + 3) * L2C);
        float c0 = cosf(a0), s0 = sinf(a0);
        float c1 = cosf(a1), s1 = sinf(a1);
        float c2 = cosf(a2), s2 = sinf(a2);
        float c3 = cosf(a3), s3 = sinf(a3);
        float4 qa, qb, ka, kb;
        qa.x = q1.x * c0 - q2.x * s0;  qb.x = q2.x * c0 + q1.x * s0;
        qa.y = q1.y * c1 - q2.y * s1;  qb.y = q2.y * c1 + q1.y * s1;
        qa.z = q1.z * c2 - q2.z * s2;  qb.z = q2.z * c2 + q1.z * s2;
        qa.w = q1.w * c3 - q2.w * s3;  qb.w = q2.w * c3 + q1.w * s3;
        ka.x = k1.x * c0 - k2.x * s0;  kb.x = k2.x * c0 + k1.x * s0;
        ka.y = k1.y * c1 - k2.y * s1;  kb.y = k2.y * c1 + k1.y * s1;
        ka.z = k1.z * c2 - k2.z * s2;  kb.z = k2.z * c2 + k1.z * s2;
        ka.w = k1.w * c3 - k2.w * s3;  kb.w = k2.w * c3 + k1.w * s3;
        *reinterpret_cast<float4*>(&q_s[aswz(tq, cg)])      = qa;
        *reinterpret_cast<float4*>(&q_s[aswz(tq, cg + 16)]) = qb;
        *reinterpret_cast<float4*>(&k_s[aswz(tq, cg)])      = ka;
        *reinterpret_cast<float4*>(&k_s[aswz(tq, cg + 16)]) = kb;
    }
    __syncthreads();
    int qi = tid >> 2;
    int g  = tid & 3;
    float pv[16];
    #pragma unroll
    for (int j = 0; j < 16; ++j) pv[j] = 0.f;
    for (int c = 0; c < 32; ++c) {
        float4 a = *reinterpret_cast<const float4*>(&q_s[aswz(qi, c)]);
        #pragma unroll
        for (int j = 0; j < 16; ++j) {
            int ki = (j << 2) + g;
            float4 bb = *reinterpret_cast<const float4*>(&k_s[aswz(ki, c)]);
            pv[j] += a.x * bb.x + a.y * bb.y + a.z * bb.z + a.w * bb.w;
        }
    }
    const float scale = 0.0883883476483184405f;   // 128^-0.5
    float m = -1e30f;
    #pragma unroll
    for (int j = 0; j < 16; ++j) {
        int ki = (j << 2) + g;
        pv[j] = (ki <= qi) ? pv[j] * scale : -1e30f;
        m = fmaxf(m, pv[j]);
    }
    m = fmaxf(m, __shfl_xor(m, 1));
    m = fmaxf(m, __shfl_xor(m, 2));
    float l = 0.f;
    #pragma unroll
    for (int j = 0; j < 16; ++j) {
        float e = (pv[j] > -1e29f) ? expf(pv[j] - m) : 0.f;
        pv[j] = e;
        l += e;
    }
    l += __shfl_xor(l, 1);
    l += __shfl_xor(l, 2);
    float inv_l = 1.f / l;
    __syncthreads();                  // all waves done with q_s/k_s reads
    float* p_s = q_s;                 // [64][65], unswizzled
    #pragma unroll
    for (int j = 0; j < 16; ++j) p_s[qi * 65 + (j << 2) + g] = pv[j] * inv_l;
    float* v_s = k_s;                 // stage V swizzled into k_s
    #pragma unroll
    for (int r = 0; r < 8; ++r) {
        int idx = tid + (r << 8);
        int tv = idx >> 5;            // 0..63
        int c = idx & 31;             // chunk 0..31
        *reinterpret_cast<float4*>(&v_s[aswz(tv, c)]) =
            *reinterpret_cast<const float4*>(base + (size_t)tv * 6144 + 4096 + (c << 2));
    }
    __syncthreads();
    // PV: thread (qi,g) owns dims g*4 + u*16 (+0..3), u=0..7 -> chunk g+4u.
    float4 acc[8];
    #pragma unroll
    for (int u = 0; u < 8; ++u) acc[u] = {0.f, 0.f, 0.f, 0.f};
    for (int ki = 0; ki < 64; ++ki) {
        float p = p_s[qi * 65 + ki];
        #pragma unroll
        for (int u = 0; u < 8; ++u) {
            float4 vv = *reinterpret_cast<const float4*>(&v_s[aswz(ki, g + (u << 2))]);
            acc[u].x += p * vv.x;
            acc[u].y += p * vv.y;
            acc[u].z += p * vv.z;
            acc[u].w += p * vv.w;
        }
    }
    __bf16* orow = attn_out + (size_t)(b * 64 + qi) * 2048 + h * 128 + (g << 2);
    #pragma unroll
    for (int u = 0; u < 8; ++u) {
        Pack4 p4;
        p4.h[0] = (__bf16)acc[u].x; p4.h[1] = (__bf16)acc[u].y;
        p4.h[2] = (__bf16)acc[u].z; p4.h[3] = (__bf16)acc[u].w;
        *reinterpret_cast<uint2*>(orow + (u << 4)) = p4.u;
    }
}

// ---------------------------------------------------------------------------
// 4) Outputs: blocks 0..2047 broadcast video; 2048..2175 copy audio. f32.
__global__ __launch_bounds__(256) void outputs_kernel(
    const float* __restrict__ outp, float* __restrict__ d_out)
{
    int bid = blockIdx.x;
    if (bid < 2048) {
        int which = bid >> 10;
        int rem = bid & 1023;
        int row = rem >> 4;             // b*16 + t
        int schunk = rem & 15;
        int b = row >> 4;
        int t = row & 15;
        const float* src = outp + (size_t)(b * 64 + (which << 4) + t) * 2048 + threadIdx.x * 8;
        float4 o0 = *reinterpret_cast<const float4*>(src);
        float4 o1 = *reinterpret_cast<const float4*>(src + 4);
        size_t base = (size_t)which * 33554432 +
                      ((size_t)row * 256 + (size_t)schunk * 16) * 2048 + threadIdx.x * 8;
        float* dst = d_out + base;
        #pragma unroll
        for (int s = 0; s < 16; ++s) {
            *reinterpret_cast<float4*>(dst + (size_t)s * 2048)     = o0;
            *reinterpret_cast<float4*>(dst + (size_t)s * 2048 + 4) = o1;
        }
    } else {
        int g8 = (bid - 2048) * 256 + threadIdx.x;  // 8-float group, 0..32767
        int which = g8 >> 14;
        int j = g8 & 16383;
        int b = j >> 12;
        int rr = j & 4095;
        int tt = rr >> 8;
        int gq = rr & 255;
        const float* src = outp + (size_t)(b * 64 + 32 + (which << 4) + tt) * 2048 + gq * 8;
        float4 x0 = *reinterpret_cast<const float4*>(src);
        float4 x1 = *reinterpret_cast<const float4*>(src + 4);
        float* dst = d_out + 67108864 + (size_t)which * 131072 +
                     (size_t)(b * 16 + tt) * 2048 + gq * 8;
        *reinterpret_cast<float4*>(dst)     = x0;
        *reinterpret_cast<float4*>(dst + 4) = x1;
    }
}

// ---------------------------------------------------------------------------
extern "C" void kernel_launch(void* const* d_in, const int* in_sizes, int n_in,
                              void* d_out, int out_size, void* d_ws, size_t ws_size,
                              hipStream_t stream)
{
    const float* v_p    = (const float*)d_in[0];
    const float* v_f    = (const float*)d_in[1];
    const float* a_p    = (const float*)d_in[2];
    const float* a_f    = (const float*)d_in[3];
    const float* W_qkv  = (const float*)d_in[4];
    const float* W_proj = (const float*)d_in[5];
    const float* b_proj = (const float*)d_in[6];
    float* out_f = (float*)d_out;

    char* ws = (char*)d_ws;
    __bf16* tokens_bf = (__bf16*)(ws);                       // 1 MB
    __bf16* Wt_qkv    = (__bf16*)(ws + 1048576);             // 24 MB
    __bf16* Wt_proj   = (__bf16*)(ws + 26214400);            // 8 MB
    float*  qkv       = (float*)(ws + 34603008);             // 6 MB
    __bf16* attn_bf   = (__bf16*)(ws + 40894464);            // 1 MB
    float*  outp      = (float*)(ws + 41943040);             // 2 MB
    float*  partials  = (float*)(ws + 44040192);             // 8 MB

    prep_mean_kernel<<<6144, 256, 0, stream>>>(v_p, v_f, partials,
                                               W_qkv, W_proj, Wt_qkv, Wt_proj);
    tokens_finish_kernel<<<256, 256, 0, stream>>>(partials, a_p, a_f, tokens_bf);
    gemm_bf16_kernel<<<dim3(96, 4), 256, 0, stream>>>(tokens_bf, Wt_qkv, nullptr, qkv, 6144);
    attn_kernel<<<64, 256, 0, stream>>>(qkv, attn_bf);
    gemm_bf16_kernel<<<dim3(32, 4), 256, 0, stream>>>(attn_bf, Wt_proj, b_proj, outp, 2048);
    outputs_kernel<<<2176, 256, 0, stream>>>(outp, out_f);
}